// Round 2
// baseline (727.123 us; speedup 1.0000x reference)
//
#include <hip/hip_runtime.h>
#include <hip/hip_bf16.h>

typedef __bf16 bf16x8 __attribute__((ext_vector_type(8)));
typedef float f32x4 __attribute__((ext_vector_type(4)));
typedef short short8 __attribute__((ext_vector_type(8)));
typedef short short4v __attribute__((ext_vector_type(4)));

#define NB 4
#define CC 256
#define SS 4096
#define EE 256

static constexpr float QSCALE = 1.4426950408889634f / 16.0f;  // log2(e)/sqrt(E)

// workspace offsets (bytes)
#define QOFF 0u
#define KOFF 8388608u
#define VOFF 16777216u
#define WOFF 25165824u
#define BOFF 25559040u
#define PAOFF 25690112u   // partial acc (f32 [slot][256 o][64 s]) then stats (float2 [slot][64 s])

// ---------------- weight prep: fp32 -> bf16 (q rows pre-scaled) ----------------
__global__ __launch_bounds__(256) void prep_kernel(const float* __restrict__ Wq,
                                                   const float* __restrict__ bq,
                                                   const float* __restrict__ Wkv,
                                                   const float* __restrict__ bkv,
                                                   __bf16* __restrict__ wc,
                                                   float* __restrict__ bias) {
    int r = blockIdx.x;   // 0..767 concat row: [0,256)=q, [256,512)=k, [512,768)=v
    int t = threadIdx.x;  // channel
    float v;
    if (r < 256) v = Wq[r * 256 + t] * QSCALE;
    else         v = Wkv[(r - 256) * 256 + t];
    wc[r * 256 + t] = (__bf16)v;
    if (t == 0) bias[r] = (r < 256) ? bq[r] * QSCALE : bkv[r - 256];
}

// ---------------- projection: q,k [n][S][E] bf16 ; v transposed [n][O][S] bf16 ----------------
__global__ __launch_bounds__(256) void proj_kernel(const float* __restrict__ x,
                                                   const __bf16* __restrict__ wc,
                                                   const float* __restrict__ bias,
                                                   __bf16* __restrict__ qo,
                                                   __bf16* __restrict__ ko,
                                                   __bf16* __restrict__ vo) {
    __shared__ __align__(16) char Ab[32768];  // x^T tile [64 s][256 c] bf16, swizzled
    __shared__ __align__(16) char Wb[32768];  // W tile  [64 o][256 c] bf16, swizzled (aliased as T in epilogue)
    const int t = threadIdx.x;
    const int lane = t & 63;
    const int w = t >> 6;
    const int n = blockIdx.x >> 6;
    const int s0 = (blockIdx.x & 63) << 6;

    // ---- stage A: transpose x[n][c][s0+0..63] (f32) -> Ab[s][c] bf16
    {
        const int sl = t & 15;
        const int cc0 = t >> 4;  // 0..15
        #pragma unroll
        for (int it = 0; it < 2; ++it) {
            int c0 = (cc0 + (it << 4)) << 3;  // c chunk base
            float f[8][4];
            #pragma unroll
            for (int r = 0; r < 8; ++r) {
                const float* xp = x + ((long)(n * CC + c0 + r)) * SS + s0 + sl;
                #pragma unroll
                for (int i = 0; i < 4; ++i) f[r][i] = xp[i << 4];
            }
            #pragma unroll
            for (int i = 0; i < 4; ++i) {
                bf16x8 v;
                #pragma unroll
                for (int r = 0; r < 8; ++r) v[r] = (__bf16)f[r][i];
                int srow = sl + (i << 4);
                *(bf16x8*)(Ab + srow * 512 + ((c0 * 2) ^ ((srow & 7) << 4))) = v;
            }
        }
    }
    __syncthreads();

    // hoisted A fragments (this wave's 16 s-rows), reused for all 12 o-tiles
    bf16x8 af[8];
    {
        int arow = (w << 4) + (lane & 15);
        #pragma unroll
        for (int kf = 0; kf < 8; ++kf) {
            int c = ((lane >> 4) << 3) + (kf << 5);
            af[kf] = *(const bf16x8*)(Ab + arow * 512 + ((c * 2) ^ ((arow & 7) << 4)));
        }
    }

    for (int ot = 0; ot < 12; ++ot) {
        // ---- stage W tile (bf16 copy, already converted)
        #pragma unroll
        for (int p = 0; p < 16; ++p) {
            int row = w + (p << 2);
            int c = lane << 2;
            short4v vv = *(const short4v*)((const short*)wc + (ot * 64 + row) * 256 + c);
            *(short4v*)(Wb + row * 512 + ((c * 2) ^ ((row & 7) << 4))) = vv;
        }
        __syncthreads();

        f32x4 acc[4];
        #pragma unroll
        for (int cb = 0; cb < 4; ++cb) acc[cb] = (f32x4){0.f, 0.f, 0.f, 0.f};
        #pragma unroll
        for (int cb = 0; cb < 4; ++cb) {
            int row = (cb << 4) + (lane & 15);
            #pragma unroll
            for (int kf = 0; kf < 8; ++kf) {
                int c = ((lane >> 4) << 3) + (kf << 5);
                bf16x8 bfr = *(const bf16x8*)(Wb + row * 512 + ((c * 2) ^ ((row & 7) << 4)));
                acc[cb] = __builtin_amdgcn_mfma_f32_16x16x32_bf16(af[kf], bfr, acc[cb], 0, 0, 0);
            }
        }
        __syncthreads();  // W reads done; reuse Wb as transpose buffer T

        __bf16* T = (__bf16*)Wb;  // [64][72] padded
        float bsv[4];
        #pragma unroll
        for (int cb = 0; cb < 4; ++cb) bsv[cb] = bias[ot * 64 + (cb << 4) + (lane & 15)];

        if (ot < 8) {  // q or k : T[s][o]
            #pragma unroll
            for (int cb = 0; cb < 4; ++cb) {
                #pragma unroll
                for (int jj = 0; jj < 4; ++jj) {
                    int srow = (w << 4) + ((lane >> 4) << 2) + jj;
                    T[srow * 72 + (cb << 4) + (lane & 15)] = (__bf16)(acc[cb][jj] + bsv[cb]);
                }
            }
            __syncthreads();
            int s = t >> 2;
            int o0 = (t & 3) << 4;
            short8 r0 = *(const short8*)((const short*)T + s * 72 + o0);
            short8 r1 = *(const short8*)((const short*)T + s * 72 + o0 + 8);
            __bf16* dst = (ot < 4) ? qo : ko;
            long idx = ((long)(n * SS + s0 + s)) * EE + ((ot & 3) << 6) + o0;
            *(short8*)((short*)dst + idx) = r0;
            *(short8*)((short*)dst + idx + 8) = r1;
        } else {       // v : T[o][s] -> vo[n][o][s]
            #pragma unroll
            for (int cb = 0; cb < 4; ++cb) {
                #pragma unroll
                for (int jj = 0; jj < 4; ++jj) {
                    int srow = (w << 4) + ((lane >> 4) << 2) + jj;
                    T[((cb << 4) + (lane & 15)) * 72 + srow] = (__bf16)(acc[cb][jj] + bsv[cb]);
                }
            }
            __syncthreads();
            int o = t >> 2;
            int sc0 = (t & 3) << 4;
            short8 r0 = *(const short8*)((const short*)T + o * 72 + sc0);
            short8 r1 = *(const short8*)((const short*)T + o * 72 + sc0 + 8);
            long idx = ((long)((n << 8) + ((ot - 8) << 6) + o)) * SS + s0 + sc0;
            *(short8*)((short*)vo + idx) = r0;
            *(short8*)((short*)vo + idx + 8) = r1;
        }
        __syncthreads();
    }
}

// ---------------- causal flash attention, split-KV ----------------
// grid = 256<<mcshift blocks; block -> (n, qt, chunk c). chunk covers kv-tiles [c<<chshift, min(qt, ...+CH-1)].
// direct: single-chunk mode writes normalized out; else raw partials + stats to ws.
__global__ __launch_bounds__(256) void attn_kernel(const __bf16* __restrict__ qg,
                                                   const __bf16* __restrict__ kg,
                                                   const __bf16* __restrict__ vg,
                                                   float* __restrict__ out,
                                                   float* __restrict__ pacc,
                                                   float2* __restrict__ pstats,
                                                   int chshift, int mcshift, int direct) {
    __shared__ __align__(16) char U[36864];          // union: K tile (32KB swz) / V^T tile [256][72] / out-transpose [64][68] f32
    __shared__ __align__(16) __bf16 P[4][16][72];    // per-wave P transpose buffer
    const int t = threadIdx.x;
    const int lane = t & 63;
    const int w = t >> 6;

    // XCD-chunked swizzle (nwg = 256<<mcshift, multiple of 8)
    int b = blockIdx.x;
    {
        int cpx = gridDim.x >> 3;
        b = (b & 7) * cpx + (b >> 3);
    }
    const int c = b & ((1 << mcshift) - 1);
    const int qtn = b >> mcshift;
    const int qt = qtn & 63;
    const int n = qtn >> 6;
    const int jlo = c << chshift;
    if (jlo > qt) return;
    const int jhi = (qt < jlo + (1 << chshift) - 1) ? qt : (jlo + (1 << chshift) - 1);
    const int s0 = qt << 6;

    // Q fragments in registers (scaled by log2e/16 at projection time)
    bf16x8 qf[8];
    {
        int qrow = s0 + (w << 4) + (lane & 15);
        const short* qp = (const short*)qg + ((long)(n * SS + qrow)) * EE;
        #pragma unroll
        for (int kf = 0; kf < 8; ++kf) {
            int cc = ((lane >> 4) << 3) + (kf << 5);
            qf[kf] = *(const bf16x8*)(qp + cc);
        }
    }

    float m_[4], ls[4];
    #pragma unroll
    for (int jj = 0; jj < 4; ++jj) { m_[jj] = -3e38f; ls[jj] = 0.f; }
    f32x4 acc[16];
    #pragma unroll
    for (int ocb = 0; ocb < 16; ++ocb) acc[ocb] = (f32x4){0.f, 0.f, 0.f, 0.f};

    for (int j = jlo; j <= jhi; ++j) {
        const int t0 = j << 6;
        __syncthreads();  // previous iter's V reads done before K overwrite
        // ---- stage K [64][256] bf16, XOR-swizzled
        #pragma unroll
        for (int p = 0; p < 16; ++p) {
            int row = w + (p << 2);
            int cc = lane << 2;
            short4v vv = *(const short4v*)((const short*)kg + ((long)(n * SS + t0 + row)) * EE + cc);
            *(short4v*)(U + row * 512 + ((cc * 2) ^ ((row & 7) << 4))) = vv;
        }
        __syncthreads();

        // ---- S = Q K^T (this wave: 16 q-rows x 64 keys)
        f32x4 sacc[4];
        #pragma unroll
        for (int cb = 0; cb < 4; ++cb) sacc[cb] = (f32x4){0.f, 0.f, 0.f, 0.f};
        __builtin_amdgcn_s_setprio(1);
        #pragma unroll
        for (int cb = 0; cb < 4; ++cb) {
            int row = (cb << 4) + (lane & 15);
            #pragma unroll
            for (int kf = 0; kf < 8; ++kf) {
                int cc = ((lane >> 4) << 3) + (kf << 5);
                bf16x8 kb = *(const bf16x8*)(U + row * 512 + ((cc * 2) ^ ((row & 7) << 4)));
                sacc[cb] = __builtin_amdgcn_mfma_f32_16x16x32_bf16(qf[kf], kb, sacc[cb], 0, 0, 0);
            }
        }
        __builtin_amdgcn_s_setprio(0);
        if (j == qt) {  // causal mask on diagonal tile
            #pragma unroll
            for (int cb = 0; cb < 4; ++cb) {
                int key = t0 + (cb << 4) + (lane & 15);
                #pragma unroll
                for (int jj = 0; jj < 4; ++jj) {
                    int qr = s0 + (w << 4) + ((lane >> 4) << 2) + jj;
                    if (key > qr) sacc[cb][jj] = -1e30f;
                }
            }
        }
        // ---- online softmax (base-2; rows live in 16-lane groups)
        float pv[4][4];
        float scl[4];
        #pragma unroll
        for (int jj = 0; jj < 4; ++jj) {
            float mx = fmaxf(fmaxf(sacc[0][jj], sacc[1][jj]), fmaxf(sacc[2][jj], sacc[3][jj]));
            #pragma unroll
            for (int off = 1; off < 16; off <<= 1) mx = fmaxf(mx, __shfl_xor(mx, off));
            float mn = fmaxf(m_[jj], mx);
            float sc = exp2f(m_[jj] - mn);
            m_[jj] = mn;
            float ps = 0.f;
            #pragma unroll
            for (int cb = 0; cb < 4; ++cb) { float e = exp2f(sacc[cb][jj] - mn); pv[cb][jj] = e; ps += e; }
            #pragma unroll
            for (int off = 1; off < 16; off <<= 1) ps += __shfl_xor(ps, off);
            ls[jj] = ls[jj] * sc + ps;
            scl[jj] = sc;
        }
        #pragma unroll
        for (int ocb = 0; ocb < 16; ++ocb) {
            #pragma unroll
            for (int jj = 0; jj < 4; ++jj) acc[ocb][jj] *= scl[jj];
        }
        // ---- P -> bf16 via per-wave LDS transpose
        #pragma unroll
        for (int cb = 0; cb < 4; ++cb) {
            #pragma unroll
            for (int jj = 0; jj < 4; ++jj)
                P[w][((lane >> 4) << 2) + jj][(cb << 4) + (lane & 15)] = (__bf16)pv[cb][jj];
        }
        __syncthreads();  // K reads done before V overwrites U (also orders P)
        // ---- stage V^T tile: U2[o 256][s 64] (row stride 72 elems)
        #pragma unroll
        for (int p = 0; p < 4; ++p) {
            int o = (t >> 2) + (p << 6);
            int sj = (t & 3) << 4;
            const short* vp = (const short*)vg + ((long)((n << 8) + o)) * SS + t0 + sj;
            short8 a0 = *(const short8*)vp;
            short8 a1 = *(const short8*)(vp + 8);
            *(short8*)(U + o * 144 + sj * 2) = a0;
            *(short8*)(U + o * 144 + sj * 2 + 16) = a1;
        }
        __syncthreads();
        // ---- PV accumulate
        bf16x8 pa[2];
        #pragma unroll
        for (int kf2 = 0; kf2 < 2; ++kf2)
            pa[kf2] = *(const bf16x8*)&P[w][lane & 15][((lane >> 4) << 3) + (kf2 << 5)];
        __builtin_amdgcn_s_setprio(1);
        #pragma unroll
        for (int ocb = 0; ocb < 16; ++ocb) {
            int orow = (ocb << 4) + (lane & 15);
            #pragma unroll
            for (int kf2 = 0; kf2 < 2; ++kf2) {
                bf16x8 vb = *(const bf16x8*)(U + orow * 144 + ((((lane >> 4) << 3) + (kf2 << 5)) << 1));
                acc[ocb] = __builtin_amdgcn_mfma_f32_16x16x32_bf16(pa[kf2], vb, acc[ocb], 0, 0, 0);
            }
        }
        __builtin_amdgcn_s_setprio(0);
    }

    // ---- per-row stats (partial mode)
    if (!direct && (lane & 15) == 0) {
        #pragma unroll
        for (int jj = 0; jj < 4; ++jj) {
            int s = (w << 4) + ((lane >> 4) << 2) + jj;
            pstats[(long)b * 64 + s] = make_float2(m_[jj], ls[jj]);
        }
    }

    // ---- epilogue: (optionally normalize), transpose via LDS, coalesced f32 writes
    float inv[4];
    #pragma unroll
    for (int jj = 0; jj < 4; ++jj) inv[jj] = direct ? (1.0f / ls[jj]) : 1.0f;
    float* T = (float*)U;  // [64][68]
    #pragma unroll 1
    for (int g = 0; g < 4; ++g) {
        __syncthreads();
        #pragma unroll
        for (int q4 = 0; q4 < 4; ++q4) {
            int ocb = (g << 2) + q4;
            int ol = (q4 << 4) + (lane & 15);
            #pragma unroll
            for (int jj = 0; jj < 4; ++jj)
                T[ol * 68 + (w << 4) + ((lane >> 4) << 2) + jj] = acc[ocb][jj] * inv[jj];
        }
        __syncthreads();
        int o = t >> 2;
        int sc0 = (t & 3) << 4;
        float* dp = direct ? (out + ((long)((n << 8) + (g << 6) + o)) * SS + s0 + sc0)
                           : (pacc + (long)b * 16384 + (long)((g << 6) + o) * 64 + sc0);
        #pragma unroll
        for (int u = 0; u < 4; ++u) {
            f32x4 r = *(const f32x4*)(T + o * 68 + sc0 + (u << 2));
            *(f32x4*)(dp + (u << 2)) = r;
        }
    }
}

// ---------------- combine partials: out[n][o][s] = sum_c w_c * acc_c[o][s] / L ----------------
__global__ __launch_bounds__(256) void combine_kernel(const float* __restrict__ pacc,
                                                      const float2* __restrict__ pstats,
                                                      float* __restrict__ out,
                                                      int chshift, int mcshift) {
    const int t = threadIdx.x;
    const int b = blockIdx.x;           // (n, qt, og)
    const int og = b & 3;
    const int qt = (b >> 2) & 63;
    const int n = b >> 8;
    const int nch = (qt >> chshift) + 1;
    const long slotbase = (long)((n << 6) + qt) << mcshift;

    __shared__ float wsc[8][64];
    __shared__ float invL[64];
    if (t < 64) {
        float M = -3e38f;
        for (int c2 = 0; c2 < nch; ++c2) M = fmaxf(M, pstats[(slotbase + c2) * 64 + t].x);
        float L = 0.f;
        for (int c2 = 0; c2 < nch; ++c2) {
            float2 st = pstats[(slotbase + c2) * 64 + t];
            float wv = exp2f(st.x - M);
            wsc[c2][t] = wv;
            L += st.y * wv;
        }
        invL[t] = 1.f / L;
    }
    __syncthreads();

    const int o = (og << 6) + (t >> 2);
    const int sb = (t & 3) << 4;
    f32x4 a[4];
    #pragma unroll
    for (int u = 0; u < 4; ++u) a[u] = (f32x4){0.f, 0.f, 0.f, 0.f};
    for (int c2 = 0; c2 < nch; ++c2) {
        const float* p = pacc + (slotbase + c2) * 16384 + (long)o * 64 + sb;
        #pragma unroll
        for (int u = 0; u < 4; ++u) {
            f32x4 v = *(const f32x4*)(p + (u << 2));
            #pragma unroll
            for (int k2 = 0; k2 < 4; ++k2) a[u][k2] += v[k2] * wsc[c2][sb + (u << 2) + k2];
        }
    }
    float* op = out + ((long)((n << 8) + o)) * SS + (qt << 6) + sb;
    #pragma unroll
    for (int u = 0; u < 4; ++u) {
        #pragma unroll
        for (int k2 = 0; k2 < 4; ++k2) a[u][k2] *= invL[sb + (u << 2) + k2];
        *(f32x4*)(op + (u << 2)) = a[u];
    }
}

extern "C" void kernel_launch(void* const* d_in, const int* in_sizes, int n_in,
                              void* d_out, int out_size, void* d_ws, size_t ws_size,
                              hipStream_t stream) {
    const float* x   = (const float*)d_in[0];
    const float* Wq  = (const float*)d_in[1];
    const float* bq  = (const float*)d_in[2];
    const float* Wkv = (const float*)d_in[3];
    const float* bkv = (const float*)d_in[4];
    float* out = (float*)d_out;
    char* ws = (char*)d_ws;
    __bf16* qw = (__bf16*)(ws + QOFF);
    __bf16* kw = (__bf16*)(ws + KOFF);
    __bf16* vw = (__bf16*)(ws + VOFF);
    __bf16* wc = (__bf16*)(ws + WOFF);
    float*  bias = (float*)(ws + BOFF);

    // choose split factor MC=2^mcshift (chunks per q-tile) by available workspace
    int mcshift = -1;
    for (int ms = 3; ms >= 0; --ms) {
        size_t slots = (size_t)256 << ms;
        size_t need = (size_t)PAOFF + slots * 65536 + slots * 512;
        if (need <= ws_size) { mcshift = ms; break; }
    }
    int direct = (mcshift < 0) ? 1 : 0;
    if (direct) mcshift = 0;
    int chshift = 6 - mcshift;
    float* pacc = (float*)(ws + PAOFF);
    float2* pstats = (float2*)(ws + PAOFF + (((size_t)256 << mcshift) * 65536));

    prep_kernel<<<dim3(768), dim3(256), 0, stream>>>(Wq, bq, Wkv, bkv, wc, bias);
    proj_kernel<<<dim3(256), dim3(256), 0, stream>>>(x, wc, bias, qw, kw, vw);
    attn_kernel<<<dim3(256 << mcshift), dim3(256), 0, stream>>>(qw, kw, vw, out, pacc, pstats,
                                                                chshift, mcshift, direct);
    if (!direct)
        combine_kernel<<<dim3(1024), dim3(256), 0, stream>>>(pacc, pstats, out, chshift, mcshift);
}

// Round 3
// 500.045 us; speedup vs baseline: 1.4541x; 1.4541x over previous
//
#include <hip/hip_runtime.h>
#include <hip/hip_bf16.h>

typedef __bf16 bf16x8 __attribute__((ext_vector_type(8)));
typedef float f32x4 __attribute__((ext_vector_type(4)));
typedef short short8 __attribute__((ext_vector_type(8)));
typedef short short4v __attribute__((ext_vector_type(4)));

#define NB 4
#define CC 256
#define SS 4096
#define EE 256

static constexpr float QSCALE = 1.4426950408889634f / 16.0f;  // log2(e)/sqrt(E)

// workspace offsets (bytes)
#define QOFF 0u
#define KOFF 8388608u
#define VOFF 16777216u
#define WOFF 25165824u
#define BOFF 25559040u
#define PAOFF 25690112u   // partial acc (f32 [slot][256 o][64 s]) then stats (float2 [slot][64 s])

#define GLOAD_LDS16(gsrc, ldst) \
    __builtin_amdgcn_global_load_lds((const __attribute__((address_space(1))) void*)(gsrc), \
                                     (__attribute__((address_space(3))) void*)(ldst), 16, 0, 0)

// ---------------- weight prep: fp32 -> bf16 (q rows pre-scaled) ----------------
__global__ __launch_bounds__(256) void prep_kernel(const float* __restrict__ Wq,
                                                   const float* __restrict__ bq,
                                                   const float* __restrict__ Wkv,
                                                   const float* __restrict__ bkv,
                                                   __bf16* __restrict__ wc,
                                                   float* __restrict__ bias) {
    int r = blockIdx.x;
    int t = threadIdx.x;
    float v;
    if (r < 256) v = Wq[r * 256 + t] * QSCALE;
    else         v = Wkv[(r - 256) * 256 + t];
    wc[r * 256 + t] = (__bf16)v;
    if (t == 0) bias[r] = (r < 256) ? bq[r] * QSCALE : bkv[r - 256];
}

// ---------------- projection: q,k [n][S][E] bf16 ; v transposed [n][O][S] bf16 ----------------
__global__ __launch_bounds__(256) void proj_kernel(const float* __restrict__ x,
                                                   const __bf16* __restrict__ wc,
                                                   const float* __restrict__ bias,
                                                   __bf16* __restrict__ qo,
                                                   __bf16* __restrict__ ko,
                                                   __bf16* __restrict__ vo) {
    __shared__ __align__(16) char Ab[32768];
    __shared__ __align__(16) char Wb[32768];
    const int t = threadIdx.x;
    const int lane = t & 63;
    const int w = t >> 6;
    const int n = blockIdx.x >> 6;
    const int s0 = (blockIdx.x & 63) << 6;

    {
        const int sl = t & 15;
        const int cc0 = t >> 4;
        #pragma unroll
        for (int it = 0; it < 2; ++it) {
            int c0 = (cc0 + (it << 4)) << 3;
            float f[8][4];
            #pragma unroll
            for (int r = 0; r < 8; ++r) {
                const float* xp = x + ((long)(n * CC + c0 + r)) * SS + s0 + sl;
                #pragma unroll
                for (int i = 0; i < 4; ++i) f[r][i] = xp[i << 4];
            }
            #pragma unroll
            for (int i = 0; i < 4; ++i) {
                bf16x8 v;
                #pragma unroll
                for (int r = 0; r < 8; ++r) v[r] = (__bf16)f[r][i];
                int srow = sl + (i << 4);
                *(bf16x8*)(Ab + srow * 512 + ((c0 * 2) ^ ((srow & 7) << 4))) = v;
            }
        }
    }
    __syncthreads();

    bf16x8 af[8];
    {
        int arow = (w << 4) + (lane & 15);
        #pragma unroll
        for (int kf = 0; kf < 8; ++kf) {
            int c = ((lane >> 4) << 3) + (kf << 5);
            af[kf] = *(const bf16x8*)(Ab + arow * 512 + ((c * 2) ^ ((arow & 7) << 4)));
        }
    }

    for (int ot = 0; ot < 12; ++ot) {
        #pragma unroll
        for (int p = 0; p < 16; ++p) {
            int row = w + (p << 2);
            int c = lane << 2;
            short4v vv = *(const short4v*)((const short*)wc + (ot * 64 + row) * 256 + c);
            *(short4v*)(Wb + row * 512 + ((c * 2) ^ ((row & 7) << 4))) = vv;
        }
        __syncthreads();

        f32x4 acc[4];
        #pragma unroll
        for (int cb = 0; cb < 4; ++cb) acc[cb] = (f32x4){0.f, 0.f, 0.f, 0.f};
        #pragma unroll
        for (int cb = 0; cb < 4; ++cb) {
            int row = (cb << 4) + (lane & 15);
            #pragma unroll
            for (int kf = 0; kf < 8; ++kf) {
                int c = ((lane >> 4) << 3) + (kf << 5);
                bf16x8 bfr = *(const bf16x8*)(Wb + row * 512 + ((c * 2) ^ ((row & 7) << 4)));
                acc[cb] = __builtin_amdgcn_mfma_f32_16x16x32_bf16(af[kf], bfr, acc[cb], 0, 0, 0);
            }
        }
        __syncthreads();

        __bf16* T = (__bf16*)Wb;
        float bsv[4];
        #pragma unroll
        for (int cb = 0; cb < 4; ++cb) bsv[cb] = bias[ot * 64 + (cb << 4) + (lane & 15)];

        if (ot < 8) {
            #pragma unroll
            for (int cb = 0; cb < 4; ++cb) {
                #pragma unroll
                for (int jj = 0; jj < 4; ++jj) {
                    int srow = (w << 4) + ((lane >> 4) << 2) + jj;
                    T[srow * 72 + (cb << 4) + (lane & 15)] = (__bf16)(acc[cb][jj] + bsv[cb]);
                }
            }
            __syncthreads();
            int s = t >> 2;
            int o0 = (t & 3) << 4;
            short8 r0 = *(const short8*)((const short*)T + s * 72 + o0);
            short8 r1 = *(const short8*)((const short*)T + s * 72 + o0 + 8);
            __bf16* dst = (ot < 4) ? qo : ko;
            long idx = ((long)(n * SS + s0 + s)) * EE + ((ot & 3) << 6) + o0;
            *(short8*)((short*)dst + idx) = r0;
            *(short8*)((short*)dst + idx + 8) = r1;
        } else {
            #pragma unroll
            for (int cb = 0; cb < 4; ++cb) {
                #pragma unroll
                for (int jj = 0; jj < 4; ++jj) {
                    int srow = (w << 4) + ((lane >> 4) << 2) + jj;
                    T[((cb << 4) + (lane & 15)) * 72 + srow] = (__bf16)(acc[cb][jj] + bsv[cb]);
                }
            }
            __syncthreads();
            int o = t >> 2;
            int sc0 = (t & 3) << 4;
            short8 r0 = *(const short8*)((const short*)T + o * 72 + sc0);
            short8 r1 = *(const short8*)((const short*)T + o * 72 + sc0 + 8);
            long idx = ((long)((n << 8) + ((ot - 8) << 6) + o)) * SS + s0 + sc0;
            *(short8*)((short*)vo + idx) = r0;
            *(short8*)((short*)vo + idx + 8) = r1;
        }
        __syncthreads();
    }
}

// ---------------- causal flash attention, split-KV, 1-barrier tile pipeline ----------------
__global__ __launch_bounds__(256, 2) void attn_kernel(const __bf16* __restrict__ qg,
                                                      const __bf16* __restrict__ kg,
                                                      const __bf16* __restrict__ vg,
                                                      float* __restrict__ out,
                                                      float* __restrict__ pacc,
                                                      float2* __restrict__ pstats,
                                                      int chshift, int mcshift, int direct) {
    __shared__ __align__(16) char Kb[2][32768];      // K tile double-buffer, XOR-swizzled
    __shared__ __align__(16) __bf16 P[4][16][72];    // per-wave P buffer (no cross-wave sharing)
    const int t = threadIdx.x;
    const int lane = t & 63;
    const int w = t >> 6;

    int b = blockIdx.x;
    {
        int cpx = gridDim.x >> 3;
        b = (b & 7) * cpx + (b >> 3);
    }
    const int c = b & ((1 << mcshift) - 1);
    const int qtn = b >> mcshift;
    const int qt = qtn & 63;
    const int n = qtn >> 6;
    const int jlo = c << chshift;
    if (jlo > qt) return;
    const int jhi = (qt < jlo + (1 << chshift) - 1) ? qt : (jlo + (1 << chshift) - 1);
    const int s0 = qt << 6;

    // stage K tile j into Kb[p] via async global->LDS, source pre-swizzled (m173 pattern)
    auto stageK = [&](int j, int p) {
        const int t0j = j << 6;
        #pragma unroll
        for (int i = 0; i < 8; ++i) {
            int r0 = (w << 4) + (i << 1);          // local row pair base
            int rl = r0 + (lane >> 5);             // this lane's local row
            const short* src = (const short*)kg + ((long)(n * SS + t0j + rl)) * EE
                               + (((lane & 31) << 3) ^ ((rl & 7) << 3));
            GLOAD_LDS16(src, Kb[p] + r0 * 512);
        }
    };

    // Q fragments in registers
    bf16x8 qf[8];
    {
        int qrow = s0 + (w << 4) + (lane & 15);
        const short* qp = (const short*)qg + ((long)(n * SS + qrow)) * EE;
        #pragma unroll
        for (int kf = 0; kf < 8; ++kf) {
            int cc = ((lane >> 4) << 3) + (kf << 5);
            qf[kf] = *(const bf16x8*)(qp + cc);
        }
    }

    float m_[4], ls[4];
    #pragma unroll
    for (int jj = 0; jj < 4; ++jj) { m_[jj] = -3e38f; ls[jj] = 0.f; }
    f32x4 acc[16];
    #pragma unroll
    for (int ocb = 0; ocb < 16; ++ocb) acc[ocb] = (f32x4){0.f, 0.f, 0.f, 0.f};

    const short* vbase = (const short*)vg + ((long)(n << 8)) * SS + ((lane >> 4) << 3);

    stageK(jlo, jlo & 1);

    for (int j = jlo; j <= jhi; ++j) {
        const int p = j & 1;
        const int t0 = j << 6;
        __syncthreads();   // drains vmcnt: K(j) resident; fences buffer p^1 reuse

        // ---- S = Q K^T
        f32x4 sacc[4];
        #pragma unroll
        for (int cb = 0; cb < 4; ++cb) sacc[cb] = (f32x4){0.f, 0.f, 0.f, 0.f};
        #pragma unroll
        for (int cb = 0; cb < 4; ++cb) {
            int row = (cb << 4) + (lane & 15);
            #pragma unroll
            for (int kf = 0; kf < 8; ++kf) {
                int cc = ((lane >> 4) << 3) + (kf << 5);
                bf16x8 kb = *(const bf16x8*)(Kb[p] + row * 512 + ((cc * 2) ^ ((row & 7) << 4)));
                sacc[cb] = __builtin_amdgcn_mfma_f32_16x16x32_bf16(qf[kf], kb, sacc[cb], 0, 0, 0);
            }
        }

        // ---- prefetch K(j+1) into other buffer (hidden under softmax+PV)
        if (j < jhi) stageK(j + 1, p ^ 1);

        if (j == qt) {  // causal mask on diagonal tile
            #pragma unroll
            for (int cb = 0; cb < 4; ++cb) {
                int key = t0 + (cb << 4) + (lane & 15);
                #pragma unroll
                for (int jj = 0; jj < 4; ++jj) {
                    int qr = s0 + (w << 4) + ((lane >> 4) << 2) + jj;
                    if (key > qr) sacc[cb][jj] = -1e30f;
                }
            }
        }

        // ---- online softmax, 4 rows' reduction chains interleaved
        float mx[4], ps[4], scl[4];
        #pragma unroll
        for (int jj = 0; jj < 4; ++jj)
            mx[jj] = fmaxf(fmaxf(sacc[0][jj], sacc[1][jj]), fmaxf(sacc[2][jj], sacc[3][jj]));
        #pragma unroll
        for (int off = 1; off < 16; off <<= 1) {
            #pragma unroll
            for (int jj = 0; jj < 4; ++jj) mx[jj] = fmaxf(mx[jj], __shfl_xor(mx[jj], off));
        }
        float pv[4][4];
        #pragma unroll
        for (int jj = 0; jj < 4; ++jj) {
            float mn = fmaxf(m_[jj], mx[jj]);
            scl[jj] = exp2f(m_[jj] - mn);
            m_[jj] = mn;
        }
        #pragma unroll
        for (int cb = 0; cb < 4; ++cb)
            #pragma unroll
            for (int jj = 0; jj < 4; ++jj) pv[cb][jj] = exp2f(sacc[cb][jj] - m_[jj]);
        #pragma unroll
        for (int jj = 0; jj < 4; ++jj)
            ps[jj] = (pv[0][jj] + pv[1][jj]) + (pv[2][jj] + pv[3][jj]);
        #pragma unroll
        for (int off = 1; off < 16; off <<= 1) {
            #pragma unroll
            for (int jj = 0; jj < 4; ++jj) ps[jj] += __shfl_xor(ps[jj], off);
        }
        #pragma unroll
        for (int jj = 0; jj < 4; ++jj) ls[jj] = ls[jj] * scl[jj] + ps[jj];

        // ---- P -> per-wave LDS (write early so lgkm hides under rescale)
        #pragma unroll
        for (int cb = 0; cb < 4; ++cb)
            #pragma unroll
            for (int jj = 0; jj < 4; ++jj)
                P[w][((lane >> 4) << 2) + jj][(cb << 4) + (lane & 15)] = (__bf16)pv[cb][jj];

        #pragma unroll
        for (int ocb = 0; ocb < 16; ++ocb)
            #pragma unroll
            for (int jj = 0; jj < 4; ++jj) acc[ocb][jj] *= scl[jj];

        // ---- PV: P from own-wave LDS, V fragments direct from global (L2-resident)
        bf16x8 pa[2];
        #pragma unroll
        for (int kf2 = 0; kf2 < 2; ++kf2)
            pa[kf2] = *(const bf16x8*)&P[w][lane & 15][((lane >> 4) << 3) + (kf2 << 5)];
        #pragma unroll
        for (int ocb = 0; ocb < 16; ++ocb) {
            int orow = (ocb << 4) + (lane & 15);
            const short* vp = vbase + (long)orow * SS + t0;
            #pragma unroll
            for (int kf2 = 0; kf2 < 2; ++kf2) {
                bf16x8 vb = *(const bf16x8*)(vp + (kf2 << 5));
                acc[ocb] = __builtin_amdgcn_mfma_f32_16x16x32_bf16(pa[kf2], vb, acc[ocb], 0, 0, 0);
            }
        }
    }

    // ---- per-row stats (partial mode)
    if (!direct && (lane & 15) == 0) {
        #pragma unroll
        for (int jj = 0; jj < 4; ++jj) {
            int s = (w << 4) + ((lane >> 4) << 2) + jj;
            pstats[(long)b * 64 + s] = make_float2(m_[jj], ls[jj]);
        }
    }

    // ---- epilogue: transpose via LDS (reuse Kb), coalesced f32 writes
    float inv[4];
    #pragma unroll
    for (int jj = 0; jj < 4; ++jj) inv[jj] = direct ? (1.0f / ls[jj]) : 1.0f;
    float* T = (float*)Kb;  // [64][68]
    #pragma unroll 1
    for (int g = 0; g < 4; ++g) {
        __syncthreads();
        #pragma unroll
        for (int q4 = 0; q4 < 4; ++q4) {
            int ocb = (g << 2) + q4;
            int ol = (q4 << 4) + (lane & 15);
            #pragma unroll
            for (int jj = 0; jj < 4; ++jj)
                T[ol * 68 + (w << 4) + ((lane >> 4) << 2) + jj] = acc[ocb][jj] * inv[jj];
        }
        __syncthreads();
        int o = t >> 2;
        int sc0 = (t & 3) << 4;
        float* dp = direct ? (out + ((long)((n << 8) + (g << 6) + o)) * SS + s0 + sc0)
                           : (pacc + (long)b * 16384 + (long)((g << 6) + o) * 64 + sc0);
        #pragma unroll
        for (int u = 0; u < 4; ++u) {
            f32x4 r = *(const f32x4*)(T + o * 68 + sc0 + (u << 2));
            *(f32x4*)(dp + (u << 2)) = r;
        }
    }
}

// ---------------- combine partials ----------------
__global__ __launch_bounds__(256) void combine_kernel(const float* __restrict__ pacc,
                                                      const float2* __restrict__ pstats,
                                                      float* __restrict__ out,
                                                      int chshift, int mcshift) {
    const int t = threadIdx.x;
    const int b = blockIdx.x;
    const int og = b & 3;
    const int qt = (b >> 2) & 63;
    const int n = b >> 8;
    const int nch = (qt >> chshift) + 1;
    const long slotbase = (long)((n << 6) + qt) << mcshift;

    __shared__ float wsc[8][64];
    __shared__ float invL[64];
    if (t < 64) {
        float M = -3e38f;
        for (int c2 = 0; c2 < nch; ++c2) M = fmaxf(M, pstats[(slotbase + c2) * 64 + t].x);
        float L = 0.f;
        for (int c2 = 0; c2 < nch; ++c2) {
            float2 st = pstats[(slotbase + c2) * 64 + t];
            float wv = exp2f(st.x - M);
            wsc[c2][t] = wv;
            L += st.y * wv;
        }
        invL[t] = 1.f / L;
    }
    __syncthreads();

    const int o = (og << 6) + (t >> 2);
    const int sb = (t & 3) << 4;
    f32x4 a[4];
    #pragma unroll
    for (int u = 0; u < 4; ++u) a[u] = (f32x4){0.f, 0.f, 0.f, 0.f};
    for (int c2 = 0; c2 < nch; ++c2) {
        const float* p = pacc + (slotbase + c2) * 16384 + (long)o * 64 + sb;
        #pragma unroll
        for (int u = 0; u < 4; ++u) {
            f32x4 v = *(const f32x4*)(p + (u << 2));
            #pragma unroll
            for (int k2 = 0; k2 < 4; ++k2) a[u][k2] += v[k2] * wsc[c2][sb + (u << 2) + k2];
        }
    }
    float* op = out + ((long)((n << 8) + o)) * SS + (qt << 6) + sb;
    #pragma unroll
    for (int u = 0; u < 4; ++u) {
        #pragma unroll
        for (int k2 = 0; k2 < 4; ++k2) a[u][k2] *= invL[sb + (u << 2) + k2];
        *(f32x4*)(op + (u << 2)) = a[u];
    }
}

extern "C" void kernel_launch(void* const* d_in, const int* in_sizes, int n_in,
                              void* d_out, int out_size, void* d_ws, size_t ws_size,
                              hipStream_t stream) {
    const float* x   = (const float*)d_in[0];
    const float* Wq  = (const float*)d_in[1];
    const float* bq  = (const float*)d_in[2];
    const float* Wkv = (const float*)d_in[3];
    const float* bkv = (const float*)d_in[4];
    float* out = (float*)d_out;
    char* ws = (char*)d_ws;
    __bf16* qw = (__bf16*)(ws + QOFF);
    __bf16* kw = (__bf16*)(ws + KOFF);
    __bf16* vw = (__bf16*)(ws + VOFF);
    __bf16* wc = (__bf16*)(ws + WOFF);
    float*  bias = (float*)(ws + BOFF);

    int mcshift = -1;
    for (int ms = 3; ms >= 0; --ms) {
        size_t slots = (size_t)256 << ms;
        size_t need = (size_t)PAOFF + slots * 65536 + slots * 512;
        if (need <= ws_size) { mcshift = ms; break; }
    }
    int direct = (mcshift < 0) ? 1 : 0;
    if (direct) mcshift = 0;
    int chshift = 6 - mcshift;
    float* pacc = (float*)(ws + PAOFF);
    float2* pstats = (float2*)(ws + PAOFF + (((size_t)256 << mcshift) * 65536));

    prep_kernel<<<dim3(768), dim3(256), 0, stream>>>(Wq, bq, Wkv, bkv, wc, bias);
    proj_kernel<<<dim3(256), dim3(256), 0, stream>>>(x, wc, bias, qw, kw, vw);
    attn_kernel<<<dim3(256 << mcshift), dim3(256), 0, stream>>>(qw, kw, vw, out, pacc, pstats,
                                                                chshift, mcshift, direct);
    if (!direct)
        combine_kernel<<<dim3(1024), dim3(256), 0, stream>>>(pacc, pstats, out, chshift, mcshift);
}

// Round 4
// 384.154 us; speedup vs baseline: 1.8928x; 1.3017x over previous
//
#include <hip/hip_runtime.h>
#include <hip/hip_bf16.h>

typedef __bf16 bf16x8 __attribute__((ext_vector_type(8)));
typedef float f32x4 __attribute__((ext_vector_type(4)));
typedef short short8 __attribute__((ext_vector_type(8)));
typedef short short4v __attribute__((ext_vector_type(4)));

#define NB 4
#define CC 256
#define SS 4096
#define EE 256

static constexpr float QSCALE = 1.4426950408889634f / 16.0f;  // log2(e)/sqrt(E)

// workspace offsets (bytes)
#define QOFF 0u
#define KOFF 8388608u
#define VOFF 16777216u
#define WOFF 25165824u
#define BOFF 25559040u
#define PAOFF 25690112u   // partial acc (f32 [slot][256 o][64 s]) then stats (float2 [slot][64 s])

#define GLOAD_LDS16(gsrc, ldst) \
    __builtin_amdgcn_global_load_lds((const __attribute__((address_space(1))) void*)(gsrc), \
                                     (__attribute__((address_space(3))) void*)(ldst), 16, 0, 0)

// ---------------- weight prep: fp32 -> bf16 (q rows pre-scaled) ----------------
__global__ __launch_bounds__(256) void prep_kernel(const float* __restrict__ Wq,
                                                   const float* __restrict__ bq,
                                                   const float* __restrict__ Wkv,
                                                   const float* __restrict__ bkv,
                                                   __bf16* __restrict__ wc,
                                                   float* __restrict__ bias) {
    int r = blockIdx.x;
    int t = threadIdx.x;
    float v;
    if (r < 256) v = Wq[r * 256 + t] * QSCALE;
    else         v = Wkv[(r - 256) * 256 + t];
    wc[r * 256 + t] = (__bf16)v;
    if (t == 0) bias[r] = (r < 256) ? bq[r] * QSCALE : bkv[r - 256];
}

// ---------------- projection: q,k [n][S][E] bf16 ; v transposed [n][O][S] bf16 ----------------
__global__ __launch_bounds__(256) void proj_kernel(const float* __restrict__ x,
                                                   const __bf16* __restrict__ wc,
                                                   const float* __restrict__ bias,
                                                   __bf16* __restrict__ qo,
                                                   __bf16* __restrict__ ko,
                                                   __bf16* __restrict__ vo) {
    __shared__ __align__(16) char Ab[32768];
    __shared__ __align__(16) char Wb[32768];
    const int t = threadIdx.x;
    const int lane = t & 63;
    const int w = t >> 6;
    const int n = blockIdx.x >> 6;
    const int s0 = (blockIdx.x & 63) << 6;

    {
        const int sl = t & 15;
        const int cc0 = t >> 4;
        #pragma unroll
        for (int it = 0; it < 2; ++it) {
            int c0 = (cc0 + (it << 4)) << 3;
            float f[8][4];
            #pragma unroll
            for (int r = 0; r < 8; ++r) {
                const float* xp = x + ((long)(n * CC + c0 + r)) * SS + s0 + sl;
                #pragma unroll
                for (int i = 0; i < 4; ++i) f[r][i] = xp[i << 4];
            }
            #pragma unroll
            for (int i = 0; i < 4; ++i) {
                bf16x8 v;
                #pragma unroll
                for (int r = 0; r < 8; ++r) v[r] = (__bf16)f[r][i];
                int srow = sl + (i << 4);
                *(bf16x8*)(Ab + srow * 512 + ((c0 * 2) ^ ((srow & 7) << 4))) = v;
            }
        }
    }
    __syncthreads();

    bf16x8 af[8];
    {
        int arow = (w << 4) + (lane & 15);
        #pragma unroll
        for (int kf = 0; kf < 8; ++kf) {
            int c = ((lane >> 4) << 3) + (kf << 5);
            af[kf] = *(const bf16x8*)(Ab + arow * 512 + ((c * 2) ^ ((arow & 7) << 4)));
        }
    }

    for (int ot = 0; ot < 12; ++ot) {
        #pragma unroll
        for (int p = 0; p < 16; ++p) {
            int row = w + (p << 2);
            int c = lane << 2;
            short4v vv = *(const short4v*)((const short*)wc + (ot * 64 + row) * 256 + c);
            *(short4v*)(Wb + row * 512 + ((c * 2) ^ ((row & 7) << 4))) = vv;
        }
        __syncthreads();

        f32x4 acc[4];
        #pragma unroll
        for (int cb = 0; cb < 4; ++cb) acc[cb] = (f32x4){0.f, 0.f, 0.f, 0.f};
        #pragma unroll
        for (int cb = 0; cb < 4; ++cb) {
            int row = (cb << 4) + (lane & 15);
            #pragma unroll
            for (int kf = 0; kf < 8; ++kf) {
                int c = ((lane >> 4) << 3) + (kf << 5);
                bf16x8 bfr = *(const bf16x8*)(Wb + row * 512 + ((c * 2) ^ ((row & 7) << 4)));
                acc[cb] = __builtin_amdgcn_mfma_f32_16x16x32_bf16(af[kf], bfr, acc[cb], 0, 0, 0);
            }
        }
        __syncthreads();

        __bf16* T = (__bf16*)Wb;
        float bsv[4];
        #pragma unroll
        for (int cb = 0; cb < 4; ++cb) bsv[cb] = bias[ot * 64 + (cb << 4) + (lane & 15)];

        if (ot < 8) {
            #pragma unroll
            for (int cb = 0; cb < 4; ++cb) {
                #pragma unroll
                for (int jj = 0; jj < 4; ++jj) {
                    int srow = (w << 4) + ((lane >> 4) << 2) + jj;
                    T[srow * 72 + (cb << 4) + (lane & 15)] = (__bf16)(acc[cb][jj] + bsv[cb]);
                }
            }
            __syncthreads();
            int s = t >> 2;
            int o0 = (t & 3) << 4;
            short8 r0 = *(const short8*)((const short*)T + s * 72 + o0);
            short8 r1 = *(const short8*)((const short*)T + s * 72 + o0 + 8);
            __bf16* dst = (ot < 4) ? qo : ko;
            long idx = ((long)(n * SS + s0 + s)) * EE + ((ot & 3) << 6) + o0;
            *(short8*)((short*)dst + idx) = r0;
            *(short8*)((short*)dst + idx + 8) = r1;
        } else {
            #pragma unroll
            for (int cb = 0; cb < 4; ++cb) {
                #pragma unroll
                for (int jj = 0; jj < 4; ++jj) {
                    int srow = (w << 4) + ((lane >> 4) << 2) + jj;
                    T[((cb << 4) + (lane & 15)) * 72 + srow] = (__bf16)(acc[cb][jj] + bsv[cb]);
                }
            }
            __syncthreads();
            int o = t >> 2;
            int sc0 = (t & 3) << 4;
            short8 r0 = *(const short8*)((const short*)T + o * 72 + sc0);
            short8 r1 = *(const short8*)((const short*)T + o * 72 + sc0 + 8);
            long idx = ((long)((n << 8) + ((ot - 8) << 6) + o)) * SS + s0 + sc0;
            *(short8*)((short*)vo + idx) = r0;
            *(short8*)((short*)vo + idx + 8) = r1;
        }
        __syncthreads();
    }
}

// ---------------- causal flash attention, split-KV, 1-barrier tile pipeline ----------------
__global__ __launch_bounds__(256, 2) void attn_kernel(const __bf16* __restrict__ qg,
                                                      const __bf16* __restrict__ kg,
                                                      const __bf16* __restrict__ vg,
                                                      float* __restrict__ out,
                                                      float* __restrict__ pacc,
                                                      float2* __restrict__ pstats,
                                                      int chshift, int mcshift, int direct) {
    __shared__ __align__(16) char Kb[2][32768];      // K tile double-buffer, XOR-swizzled
    __shared__ __align__(16) __bf16 P[4][16][72];    // per-wave P buffer
    const int t = threadIdx.x;
    const int lane = t & 63;
    const int w = t >> 6;

    int b = blockIdx.x;
    {
        int cpx = gridDim.x >> 3;
        b = (b & 7) * cpx + (b >> 3);
    }
    const int c = b & ((1 << mcshift) - 1);
    const int qtn = b >> mcshift;
    const int qt = qtn & 63;
    const int n = qtn >> 6;
    const int jlo = c << chshift;
    if (jlo > qt) return;
    const int jhi = (qt < jlo + (1 << chshift) - 1) ? qt : (jlo + (1 << chshift) - 1);
    const int s0 = qt << 6;

    auto stageK = [&](int j, int p) {
        const int t0j = j << 6;
        #pragma unroll
        for (int i = 0; i < 8; ++i) {
            int r0 = (w << 4) + (i << 1);
            int rl = r0 + (lane >> 5);
            const short* src = (const short*)kg + ((long)(n * SS + t0j + rl)) * EE
                               + (((lane & 31) << 3) ^ ((rl & 7) << 3));
            GLOAD_LDS16(src, Kb[p] + r0 * 512);
        }
    };

    // Q fragments in registers
    bf16x8 qf[8];
    {
        int qrow = s0 + (w << 4) + (lane & 15);
        const short* qp = (const short*)qg + ((long)(n * SS + qrow)) * EE;
        #pragma unroll
        for (int kf = 0; kf < 8; ++kf) {
            int cc = ((lane >> 4) << 3) + (kf << 5);
            qf[kf] = *(const bf16x8*)(qp + cc);
        }
    }

    float m_[4], ls[4];
    #pragma unroll
    for (int jj = 0; jj < 4; ++jj) { m_[jj] = -3e38f; ls[jj] = 0.f; }
    f32x4 acc[16];
    #pragma unroll
    for (int ocb = 0; ocb < 16; ++ocb) acc[ocb] = (f32x4){0.f, 0.f, 0.f, 0.f};

    const short* vbase = (const short*)vg + ((long)(n << 8)) * SS + ((lane >> 4) << 3);

    stageK(jlo, jlo & 1);

    for (int j = jlo; j <= jhi; ++j) {
        const int p = j & 1;
        const int t0 = j << 6;
        __syncthreads();   // drains vmcnt: K(j) resident; fences buffer p^1 reuse

        // ---- S = Q K^T
        f32x4 sacc[4];
        #pragma unroll
        for (int cb = 0; cb < 4; ++cb) sacc[cb] = (f32x4){0.f, 0.f, 0.f, 0.f};
        #pragma unroll
        for (int cb = 0; cb < 4; ++cb) {
            int row = (cb << 4) + (lane & 15);
            #pragma unroll
            for (int kf = 0; kf < 8; ++kf) {
                int cc = ((lane >> 4) << 3) + (kf << 5);
                bf16x8 kb = *(const bf16x8*)(Kb[p] + row * 512 + ((cc * 2) ^ ((row & 7) << 4)));
                sacc[cb] = __builtin_amdgcn_mfma_f32_16x16x32_bf16(qf[kf], kb, sacc[cb], 0, 0, 0);
            }
        }

        // ---- prefetch K(j+1) into other buffer (hidden under softmax+PV)
        if (j < jhi) stageK(j + 1, p ^ 1);

        if (j == qt) {  // causal mask on diagonal tile
            #pragma unroll
            for (int cb = 0; cb < 4; ++cb) {
                int key = t0 + (cb << 4) + (lane & 15);
                #pragma unroll
                for (int jj = 0; jj < 4; ++jj) {
                    int qr = s0 + (w << 4) + ((lane >> 4) << 2) + jj;
                    if (key > qr) sacc[cb][jj] = -1e30f;
                }
            }
        }

        // ---- online softmax, 4 rows' reduction chains interleaved
        float mx[4], ps[4], scl[4];
        #pragma unroll
        for (int jj = 0; jj < 4; ++jj)
            mx[jj] = fmaxf(fmaxf(sacc[0][jj], sacc[1][jj]), fmaxf(sacc[2][jj], sacc[3][jj]));
        #pragma unroll
        for (int off = 1; off < 16; off <<= 1) {
            #pragma unroll
            for (int jj = 0; jj < 4; ++jj) mx[jj] = fmaxf(mx[jj], __shfl_xor(mx[jj], off));
        }
        float pv[4][4];
        #pragma unroll
        for (int jj = 0; jj < 4; ++jj) {
            float mn = fmaxf(m_[jj], mx[jj]);
            scl[jj] = exp2f(m_[jj] - mn);
            m_[jj] = mn;
        }
        #pragma unroll
        for (int cb = 0; cb < 4; ++cb)
            #pragma unroll
            for (int jj = 0; jj < 4; ++jj) pv[cb][jj] = exp2f(sacc[cb][jj] - m_[jj]);
        #pragma unroll
        for (int jj = 0; jj < 4; ++jj)
            ps[jj] = (pv[0][jj] + pv[1][jj]) + (pv[2][jj] + pv[3][jj]);
        #pragma unroll
        for (int off = 1; off < 16; off <<= 1) {
            #pragma unroll
            for (int jj = 0; jj < 4; ++jj) ps[jj] += __shfl_xor(ps[jj], off);
        }
        #pragma unroll
        for (int jj = 0; jj < 4; ++jj) ls[jj] = ls[jj] * scl[jj] + ps[jj];

        // ---- P -> per-wave LDS
        #pragma unroll
        for (int cb = 0; cb < 4; ++cb)
            #pragma unroll
            for (int jj = 0; jj < 4; ++jj)
                P[w][((lane >> 4) << 2) + jj][(cb << 4) + (lane & 15)] = (__bf16)pv[cb][jj];

        #pragma unroll
        for (int ocb = 0; ocb < 16; ++ocb)
            #pragma unroll
            for (int jj = 0; jj < 4; ++jj) acc[ocb][jj] *= scl[jj];

        // ---- PV: P from own-wave LDS, V fragments direct from global (L2-resident)
        bf16x8 pa[2];
        #pragma unroll
        for (int kf2 = 0; kf2 < 2; ++kf2)
            pa[kf2] = *(const bf16x8*)&P[w][lane & 15][((lane >> 4) << 3) + (kf2 << 5)];
        #pragma unroll
        for (int ocb = 0; ocb < 16; ++ocb) {
            int orow = (ocb << 4) + (lane & 15);
            const short* vp = vbase + (long)orow * SS + t0;
            #pragma unroll
            for (int kf2 = 0; kf2 < 2; ++kf2) {
                bf16x8 vb = *(const bf16x8*)(vp + (kf2 << 5));
                acc[ocb] = __builtin_amdgcn_mfma_f32_16x16x32_bf16(pa[kf2], vb, acc[ocb], 0, 0, 0);
            }
        }
    }

    // ---- per-row stats (partial mode)
    if (!direct && (lane & 15) == 0) {
        #pragma unroll
        for (int jj = 0; jj < 4; ++jj) {
            int s = (w << 4) + ((lane >> 4) << 2) + jj;
            pstats[(long)b * 64 + s] = make_float2(m_[jj], ls[jj]);
        }
    }

    // ---- epilogue: transpose via LDS (reuse Kb), coalesced f32 writes.
    // HAND-UNROLLED over g: acc[] must only ever see compile-time indices
    // (rule #20: runtime-indexed ext_vector arrays -> scratch for the WHOLE kernel).
    float inv[4];
    #pragma unroll
    for (int jj = 0; jj < 4; ++jj) inv[jj] = direct ? (1.0f / ls[jj]) : 1.0f;
    float* T = (float*)Kb;  // [64][68]

#define EPI_STAGE(g)                                                                   \
    do {                                                                               \
        __syncthreads();                                                               \
        _Pragma("unroll")                                                              \
        for (int q4 = 0; q4 < 4; ++q4) {                                               \
            int ol = (q4 << 4) + (lane & 15);                                          \
            _Pragma("unroll")                                                          \
            for (int jj = 0; jj < 4; ++jj)                                             \
                T[ol * 68 + (w << 4) + ((lane >> 4) << 2) + jj] =                      \
                    acc[((g) << 2) + q4][jj] * inv[jj];                                \
        }                                                                              \
        __syncthreads();                                                               \
        {                                                                              \
            int o = t >> 2;                                                            \
            int sc0 = (t & 3) << 4;                                                    \
            float* dp = direct                                                         \
                ? (out + ((long)((n << 8) + ((g) << 6) + o)) * SS + s0 + sc0)          \
                : (pacc + (long)b * 16384 + (long)(((g) << 6) + o) * 64 + sc0);        \
            _Pragma("unroll")                                                          \
            for (int u = 0; u < 4; ++u) {                                              \
                f32x4 r = *(const f32x4*)(T + o * 68 + sc0 + (u << 2));                \
                *(f32x4*)(dp + (u << 2)) = r;                                          \
            }                                                                          \
        }                                                                              \
    } while (0)

    EPI_STAGE(0);
    EPI_STAGE(1);
    EPI_STAGE(2);
    EPI_STAGE(3);
#undef EPI_STAGE
}

// ---------------- combine partials ----------------
__global__ __launch_bounds__(256) void combine_kernel(const float* __restrict__ pacc,
                                                      const float2* __restrict__ pstats,
                                                      float* __restrict__ out,
                                                      int chshift, int mcshift) {
    const int t = threadIdx.x;
    const int b = blockIdx.x;
    const int og = b & 3;
    const int qt = (b >> 2) & 63;
    const int n = b >> 8;
    const int nch = (qt >> chshift) + 1;
    const long slotbase = (long)((n << 6) + qt) << mcshift;

    __shared__ float wsc[8][64];
    __shared__ float invL[64];
    if (t < 64) {
        float M = -3e38f;
        for (int c2 = 0; c2 < nch; ++c2) M = fmaxf(M, pstats[(slotbase + c2) * 64 + t].x);
        float L = 0.f;
        for (int c2 = 0; c2 < nch; ++c2) {
            float2 st = pstats[(slotbase + c2) * 64 + t];
            float wv = exp2f(st.x - M);
            wsc[c2][t] = wv;
            L += st.y * wv;
        }
        invL[t] = 1.f / L;
    }
    __syncthreads();

    const int o = (og << 6) + (t >> 2);
    const int sb = (t & 3) << 4;
    f32x4 a[4];
    #pragma unroll
    for (int u = 0; u < 4; ++u) a[u] = (f32x4){0.f, 0.f, 0.f, 0.f};
    for (int c2 = 0; c2 < nch; ++c2) {
        const float* p = pacc + (slotbase + c2) * 16384 + (long)o * 64 + sb;
        #pragma unroll
        for (int u = 0; u < 4; ++u) {
            f32x4 v = *(const f32x4*)(p + (u << 2));
            #pragma unroll
            for (int k2 = 0; k2 < 4; ++k2) a[u][k2] += v[k2] * wsc[c2][sb + (u << 2) + k2];
        }
    }
    float* op = out + ((long)((n << 8) + o)) * SS + (qt << 6) + sb;
    #pragma unroll
    for (int u = 0; u < 4; ++u) {
        #pragma unroll
        for (int k2 = 0; k2 < 4; ++k2) a[u][k2] *= invL[sb + (u << 2) + k2];
        *(f32x4*)(op + (u << 2)) = a[u];
    }
}

extern "C" void kernel_launch(void* const* d_in, const int* in_sizes, int n_in,
                              void* d_out, int out_size, void* d_ws, size_t ws_size,
                              hipStream_t stream) {
    const float* x   = (const float*)d_in[0];
    const float* Wq  = (const float*)d_in[1];
    const float* bq  = (const float*)d_in[2];
    const float* Wkv = (const float*)d_in[3];
    const float* bkv = (const float*)d_in[4];
    float* out = (float*)d_out;
    char* ws = (char*)d_ws;
    __bf16* qw = (__bf16*)(ws + QOFF);
    __bf16* kw = (__bf16*)(ws + KOFF);
    __bf16* vw = (__bf16*)(ws + VOFF);
    __bf16* wc = (__bf16*)(ws + WOFF);
    float*  bias = (float*)(ws + BOFF);

    int mcshift = -1;
    for (int ms = 3; ms >= 0; --ms) {
        size_t slots = (size_t)256 << ms;
        size_t need = (size_t)PAOFF + slots * 65536 + slots * 512;
        if (need <= ws_size) { mcshift = ms; break; }
    }
    int direct = (mcshift < 0) ? 1 : 0;
    if (direct) mcshift = 0;
    int chshift = 6 - mcshift;
    float* pacc = (float*)(ws + PAOFF);
    float2* pstats = (float2*)(ws + PAOFF + (((size_t)256 << mcshift) * 65536));

    prep_kernel<<<dim3(768), dim3(256), 0, stream>>>(Wq, bq, Wkv, bkv, wc, bias);
    proj_kernel<<<dim3(256), dim3(256), 0, stream>>>(x, wc, bias, qw, kw, vw);
    attn_kernel<<<dim3(256 << mcshift), dim3(256), 0, stream>>>(qw, kw, vw, out, pacc, pstats,
                                                                chshift, mcshift, direct);
    if (!direct)
        combine_kernel<<<dim3(1024), dim3(256), 0, stream>>>(pacc, pstats, out, chshift, mcshift);
}

// Round 5
// 199.999 us; speedup vs baseline: 3.6356x; 1.9208x over previous
//
#include <hip/hip_runtime.h>
#include <hip/hip_bf16.h>

typedef __bf16 bf16x8 __attribute__((ext_vector_type(8)));
typedef float f32x4 __attribute__((ext_vector_type(4)));
typedef short short8 __attribute__((ext_vector_type(8)));
typedef short short4v __attribute__((ext_vector_type(4)));

#define NB 4
#define CC 256
#define SS 4096
#define EE 256

static constexpr float QSCALE = 1.4426950408889634f / 16.0f;  // log2(e)/sqrt(E)

// workspace offsets (bytes)
#define QOFF 0u
#define KOFF 8388608u
#define VOFF 16777216u
#define WOFF 25165824u
#define BOFF 25559040u
#define PAOFF 25690112u   // partial acc (f32 [slot][256 o][64 s]) then stats (float2 [slot][64 s])

#define GLOAD_LDS16(gsrc, ldst) \
    __builtin_amdgcn_global_load_lds((const __attribute__((address_space(1))) void*)(gsrc), \
                                     (__attribute__((address_space(3))) void*)(ldst), 16, 0, 0)

// ---------------- weight prep: fp32 -> bf16 (q rows pre-scaled) ----------------
__global__ __launch_bounds__(256) void prep_kernel(const float* __restrict__ Wq,
                                                   const float* __restrict__ bq,
                                                   const float* __restrict__ Wkv,
                                                   const float* __restrict__ bkv,
                                                   __bf16* __restrict__ wc,
                                                   float* __restrict__ bias) {
    int r = blockIdx.x;
    int t = threadIdx.x;
    float v;
    if (r < 256) v = Wq[r * 256 + t] * QSCALE;
    else         v = Wkv[(r - 256) * 256 + t];
    wc[r * 256 + t] = (__bf16)v;
    if (t == 0) bias[r] = (r < 256) ? bq[r] * QSCALE : bkv[r - 256];
}

// ---------------- projection: q,k [n][S][E] bf16 ; v transposed [n][O][S] bf16 ----------------
__global__ __launch_bounds__(256) void proj_kernel(const float* __restrict__ x,
                                                   const __bf16* __restrict__ wc,
                                                   const float* __restrict__ bias,
                                                   __bf16* __restrict__ qo,
                                                   __bf16* __restrict__ ko,
                                                   __bf16* __restrict__ vo) {
    __shared__ __align__(16) char Ab[32768];
    __shared__ __align__(16) char Wb[32768];
    const int t = threadIdx.x;
    const int lane = t & 63;
    const int w = t >> 6;
    const int n = blockIdx.x >> 6;
    const int s0 = (blockIdx.x & 63) << 6;

    {
        const int sl = t & 15;
        const int cc0 = t >> 4;
        #pragma unroll
        for (int it = 0; it < 2; ++it) {
            int c0 = (cc0 + (it << 4)) << 3;
            float f[8][4];
            #pragma unroll
            for (int r = 0; r < 8; ++r) {
                const float* xp = x + ((long)(n * CC + c0 + r)) * SS + s0 + sl;
                #pragma unroll
                for (int i = 0; i < 4; ++i) f[r][i] = xp[i << 4];
            }
            #pragma unroll
            for (int i = 0; i < 4; ++i) {
                bf16x8 v;
                #pragma unroll
                for (int r = 0; r < 8; ++r) v[r] = (__bf16)f[r][i];
                int srow = sl + (i << 4);
                *(bf16x8*)(Ab + srow * 512 + ((c0 * 2) ^ ((srow & 7) << 4))) = v;
            }
        }
    }
    __syncthreads();

    bf16x8 af[8];
    {
        int arow = (w << 4) + (lane & 15);
        #pragma unroll
        for (int kf = 0; kf < 8; ++kf) {
            int c = ((lane >> 4) << 3) + (kf << 5);
            af[kf] = *(const bf16x8*)(Ab + arow * 512 + ((c * 2) ^ ((arow & 7) << 4)));
        }
    }

    for (int ot = 0; ot < 12; ++ot) {
        #pragma unroll
        for (int p = 0; p < 16; ++p) {
            int row = w + (p << 2);
            int c = lane << 2;
            short4v vv = *(const short4v*)((const short*)wc + (ot * 64 + row) * 256 + c);
            *(short4v*)(Wb + row * 512 + ((c * 2) ^ ((row & 7) << 4))) = vv;
        }
        __syncthreads();

        f32x4 acc[4];
        #pragma unroll
        for (int cb = 0; cb < 4; ++cb) acc[cb] = (f32x4){0.f, 0.f, 0.f, 0.f};
        #pragma unroll
        for (int cb = 0; cb < 4; ++cb) {
            int row = (cb << 4) + (lane & 15);
            #pragma unroll
            for (int kf = 0; kf < 8; ++kf) {
                int c = ((lane >> 4) << 3) + (kf << 5);
                bf16x8 bfr = *(const bf16x8*)(Wb + row * 512 + ((c * 2) ^ ((row & 7) << 4)));
                acc[cb] = __builtin_amdgcn_mfma_f32_16x16x32_bf16(af[kf], bfr, acc[cb], 0, 0, 0);
            }
        }
        __syncthreads();

        __bf16* T = (__bf16*)Wb;
        float bsv[4];
        #pragma unroll
        for (int cb = 0; cb < 4; ++cb) bsv[cb] = bias[ot * 64 + (cb << 4) + (lane & 15)];

        if (ot < 8) {
            #pragma unroll
            for (int cb = 0; cb < 4; ++cb) {
                #pragma unroll
                for (int jj = 0; jj < 4; ++jj) {
                    int srow = (w << 4) + ((lane >> 4) << 2) + jj;
                    T[srow * 72 + (cb << 4) + (lane & 15)] = (__bf16)(acc[cb][jj] + bsv[cb]);
                }
            }
            __syncthreads();
            int s = t >> 2;
            int o0 = (t & 3) << 4;
            short8 r0 = *(const short8*)((const short*)T + s * 72 + o0);
            short8 r1 = *(const short8*)((const short*)T + s * 72 + o0 + 8);
            __bf16* dst = (ot < 4) ? qo : ko;
            long idx = ((long)(n * SS + s0 + s)) * EE + ((ot & 3) << 6) + o0;
            *(short8*)((short*)dst + idx) = r0;
            *(short8*)((short*)dst + idx + 8) = r1;
        } else {
            #pragma unroll
            for (int cb = 0; cb < 4; ++cb) {
                #pragma unroll
                for (int jj = 0; jj < 4; ++jj) {
                    int srow = (w << 4) + ((lane >> 4) << 2) + jj;
                    T[((cb << 4) + (lane & 15)) * 72 + srow] = (__bf16)(acc[cb][jj] + bsv[cb]);
                }
            }
            __syncthreads();
            int o = t >> 2;
            int sc0 = (t & 3) << 4;
            short8 r0 = *(const short8*)((const short*)T + o * 72 + sc0);
            short8 r1 = *(const short8*)((const short*)T + o * 72 + sc0 + 8);
            long idx = ((long)((n << 8) + ((ot - 8) << 6) + o)) * SS + s0 + sc0;
            *(short8*)((short*)vo + idx) = r0;
            *(short8*)((short*)vo + idx + 8) = r1;
        }
        __syncthreads();
    }
}

// ---------------- causal flash attention: async KV->LDS, 2-barrier tile ----------------
__global__ __launch_bounds__(256, 2) void attn_kernel(const __bf16* __restrict__ qg,
                                                      const __bf16* __restrict__ kg,
                                                      const __bf16* __restrict__ vg,
                                                      float* __restrict__ out,
                                                      float* __restrict__ pacc,
                                                      float2* __restrict__ pstats,
                                                      int chshift, int mcshift, int direct) {
    __shared__ __align__(16) char Kb[32768];         // K tile [64][256] bf16, XOR-swizzled
    __shared__ __align__(16) char Vt[32768];         // V^T tile [256][64] bf16, XOR-swizzled
    __shared__ __align__(16) __bf16 P[4][16][72];    // per-wave P buffer
    const int t = threadIdx.x;
    const int lane = t & 63;
    const int w = t >> 6;

    int b = blockIdx.x;
    {
        int cpx = gridDim.x >> 3;
        b = (b & 7) * cpx + (b >> 3);
    }
    const int c = b & ((1 << mcshift) - 1);
    const int qtn = b >> mcshift;
    const int qt = qtn & 63;
    const int n = qtn >> 6;
    const int jlo = c << chshift;
    if (jlo > qt) return;
    const int jhi = (qt < jlo + (1 << chshift) - 1) ? qt : (jlo + (1 << chshift) - 1);
    const int s0 = qt << 6;

    // async stage K[64][256] (pre-swizzled source -> linear LDS dest; verified mechanism)
    auto stageK = [&](int j) {
        const int t0j = j << 6;
        #pragma unroll
        for (int i = 0; i < 8; ++i) {
            int r0 = (w << 4) + (i << 1);
            int rl = r0 + (lane >> 5);
            const short* src = (const short*)kg + ((long)(n * SS + t0j + rl)) * EE
                               + (((lane & 31) << 3) ^ ((rl & 7) << 3));
            GLOAD_LDS16(src, Kb + r0 * 512);
        }
    };
    // async stage V^T[256][64] from vo[n][o][s] (already transposed), swizzled source
    auto stageV = [&](int j) {
        const int t0j = j << 6;
        #pragma unroll
        for (int r = 0; r < 8; ++r) {
            int o = (r << 5) + (w << 3) + (lane >> 3);
            const char* src = (const char*)vg + (((long)((n << 8) + o)) * SS + t0j) * 2
                              + (((lane & 7) << 4) ^ (((lane >> 3) & 7) << 4));
            GLOAD_LDS16(src, Vt + (r << 12) + (w << 10));
        }
    };

    // Q fragments in registers
    bf16x8 qf[8];
    {
        int qrow = s0 + (w << 4) + (lane & 15);
        const short* qp = (const short*)qg + ((long)(n * SS + qrow)) * EE;
        #pragma unroll
        for (int kf = 0; kf < 8; ++kf) {
            int cc = ((lane >> 4) << 3) + (kf << 5);
            qf[kf] = *(const bf16x8*)(qp + cc);
        }
    }

    float m_[4], ls[4];
    #pragma unroll
    for (int jj = 0; jj < 4; ++jj) { m_[jj] = -3e38f; ls[jj] = 0.f; }
    f32x4 acc[16];
    #pragma unroll
    for (int ocb = 0; ocb < 16; ++ocb) acc[ocb] = (f32x4){0.f, 0.f, 0.f, 0.f};

    stageK(jlo);
    stageV(jlo);

    for (int j = jlo; j <= jhi; ++j) {
        const int t0 = j << 6;
        __syncthreads();   // drains vmcnt: K(j), V(j) resident in LDS

        // ---- S = Q K^T
        f32x4 sacc[4];
        #pragma unroll
        for (int cb = 0; cb < 4; ++cb) sacc[cb] = (f32x4){0.f, 0.f, 0.f, 0.f};
        #pragma unroll
        for (int cb = 0; cb < 4; ++cb) {
            int row = (cb << 4) + (lane & 15);
            #pragma unroll
            for (int kf = 0; kf < 8; ++kf) {
                int cc = ((lane >> 4) << 3) + (kf << 5);
                bf16x8 kb = *(const bf16x8*)(Kb + row * 512 + ((cc * 2) ^ ((row & 7) << 4)));
                sacc[cb] = __builtin_amdgcn_mfma_f32_16x16x32_bf16(qf[kf], kb, sacc[cb], 0, 0, 0);
            }
        }

        if (j == qt) {  // causal mask on diagonal tile
            #pragma unroll
            for (int cb = 0; cb < 4; ++cb) {
                int key = t0 + (cb << 4) + (lane & 15);
                #pragma unroll
                for (int jj = 0; jj < 4; ++jj) {
                    int qr = s0 + (w << 4) + ((lane >> 4) << 2) + jj;
                    if (key > qr) sacc[cb][jj] = -1e30f;
                }
            }
        }

        // ---- online softmax, 4 rows' reduction chains interleaved
        float mx[4], ps[4], scl[4];
        #pragma unroll
        for (int jj = 0; jj < 4; ++jj)
            mx[jj] = fmaxf(fmaxf(sacc[0][jj], sacc[1][jj]), fmaxf(sacc[2][jj], sacc[3][jj]));
        #pragma unroll
        for (int off = 1; off < 16; off <<= 1) {
            #pragma unroll
            for (int jj = 0; jj < 4; ++jj) mx[jj] = fmaxf(mx[jj], __shfl_xor(mx[jj], off));
        }
        float pv[4][4];
        #pragma unroll
        for (int jj = 0; jj < 4; ++jj) {
            float mn = fmaxf(m_[jj], mx[jj]);
            scl[jj] = exp2f(m_[jj] - mn);
            m_[jj] = mn;
        }
        #pragma unroll
        for (int cb = 0; cb < 4; ++cb)
            #pragma unroll
            for (int jj = 0; jj < 4; ++jj) pv[cb][jj] = exp2f(sacc[cb][jj] - m_[jj]);
        #pragma unroll
        for (int jj = 0; jj < 4; ++jj)
            ps[jj] = (pv[0][jj] + pv[1][jj]) + (pv[2][jj] + pv[3][jj]);
        #pragma unroll
        for (int off = 1; off < 16; off <<= 1) {
            #pragma unroll
            for (int jj = 0; jj < 4; ++jj) ps[jj] += __shfl_xor(ps[jj], off);
        }
        #pragma unroll
        for (int jj = 0; jj < 4; ++jj) ls[jj] = ls[jj] * scl[jj] + ps[jj];

        // ---- P -> per-wave LDS
        #pragma unroll
        for (int cb = 0; cb < 4; ++cb)
            #pragma unroll
            for (int jj = 0; jj < 4; ++jj)
                P[w][((lane >> 4) << 2) + jj][(cb << 4) + (lane & 15)] = (__bf16)pv[cb][jj];

        #pragma unroll
        for (int ocb = 0; ocb < 16; ++ocb)
            #pragma unroll
            for (int jj = 0; jj < 4; ++jj) acc[ocb][jj] *= scl[jj];

        // ---- PV: P and V^T both from LDS
        bf16x8 pa[2];
        #pragma unroll
        for (int kf2 = 0; kf2 < 2; ++kf2)
            pa[kf2] = *(const bf16x8*)&P[w][lane & 15][((lane >> 4) << 3) + (kf2 << 5)];
        #pragma unroll
        for (int ocb = 0; ocb < 16; ++ocb) {
            int orow = (ocb << 4) + (lane & 15);
            #pragma unroll
            for (int kf2 = 0; kf2 < 2; ++kf2) {
                int byteoff = (((lane >> 4) << 4) + (kf2 << 6)) ^ ((orow & 7) << 4);
                bf16x8 vb = *(const bf16x8*)(Vt + (orow << 7) + byteoff);
                acc[ocb] = __builtin_amdgcn_mfma_f32_16x16x32_bf16(pa[kf2], vb, acc[ocb], 0, 0, 0);
            }
        }

        __syncthreads();   // all Kb/Vt reads done; safe to overwrite
        if (j < jhi) {     // async prefetch next tile; drained by next top-of-loop barrier
            stageK(j + 1);
            stageV(j + 1);
        }
    }

    // ---- per-row stats (partial mode)
    if (!direct && (lane & 15) == 0) {
        #pragma unroll
        for (int jj = 0; jj < 4; ++jj) {
            int s = (w << 4) + ((lane >> 4) << 2) + jj;
            pstats[(long)b * 64 + s] = make_float2(m_[jj], ls[jj]);
        }
    }

    // ---- epilogue: transpose via LDS (reuse Kb), coalesced f32 writes.
    // HAND-UNROLLED over g: acc[] must only see compile-time indices (rule #20).
    float inv[4];
    #pragma unroll
    for (int jj = 0; jj < 4; ++jj) inv[jj] = direct ? (1.0f / ls[jj]) : 1.0f;
    float* T = (float*)Kb;  // [64][68]

#define EPI_STAGE(g)                                                                   \
    do {                                                                               \
        __syncthreads();                                                               \
        _Pragma("unroll")                                                              \
        for (int q4 = 0; q4 < 4; ++q4) {                                               \
            int ol = (q4 << 4) + (lane & 15);                                          \
            _Pragma("unroll")                                                          \
            for (int jj = 0; jj < 4; ++jj)                                             \
                T[ol * 68 + (w << 4) + ((lane >> 4) << 2) + jj] =                      \
                    acc[((g) << 2) + q4][jj] * inv[jj];                                \
        }                                                                              \
        __syncthreads();                                                               \
        {                                                                              \
            int o = t >> 2;                                                            \
            int sc0 = (t & 3) << 4;                                                    \
            float* dp = direct                                                         \
                ? (out + ((long)((n << 8) + ((g) << 6) + o)) * SS + s0 + sc0)          \
                : (pacc + (long)b * 16384 + (long)(((g) << 6) + o) * 64 + sc0);        \
            _Pragma("unroll")                                                          \
            for (int u = 0; u < 4; ++u) {                                              \
                f32x4 r = *(const f32x4*)(T + o * 68 + sc0 + (u << 2));                \
                *(f32x4*)(dp + (u << 2)) = r;                                          \
            }                                                                          \
        }                                                                              \
    } while (0)

    EPI_STAGE(0);
    EPI_STAGE(1);
    EPI_STAGE(2);
    EPI_STAGE(3);
#undef EPI_STAGE
}

// ---------------- combine partials ----------------
__global__ __launch_bounds__(256) void combine_kernel(const float* __restrict__ pacc,
                                                      const float2* __restrict__ pstats,
                                                      float* __restrict__ out,
                                                      int chshift, int mcshift) {
    const int t = threadIdx.x;
    const int b = blockIdx.x;
    const int og = b & 3;
    const int qt = (b >> 2) & 63;
    const int n = b >> 8;
    const int nch = (qt >> chshift) + 1;
    const long slotbase = (long)((n << 6) + qt) << mcshift;

    __shared__ float wsc[8][64];
    __shared__ float invL[64];
    if (t < 64) {
        float M = -3e38f;
        for (int c2 = 0; c2 < nch; ++c2) M = fmaxf(M, pstats[(slotbase + c2) * 64 + t].x);
        float L = 0.f;
        for (int c2 = 0; c2 < nch; ++c2) {
            float2 st = pstats[(slotbase + c2) * 64 + t];
            float wv = exp2f(st.x - M);
            wsc[c2][t] = wv;
            L += st.y * wv;
        }
        invL[t] = 1.f / L;
    }
    __syncthreads();

    const int o = (og << 6) + (t >> 2);
    const int sb = (t & 3) << 4;
    f32x4 a[4];
    #pragma unroll
    for (int u = 0; u < 4; ++u) a[u] = (f32x4){0.f, 0.f, 0.f, 0.f};
    for (int c2 = 0; c2 < nch; ++c2) {
        const float* p = pacc + (slotbase + c2) * 16384 + (long)o * 64 + sb;
        #pragma unroll
        for (int u = 0; u < 4; ++u) {
            f32x4 v = *(const f32x4*)(p + (u << 2));
            #pragma unroll
            for (int k2 = 0; k2 < 4; ++k2) a[u][k2] += v[k2] * wsc[c2][sb + (u << 2) + k2];
        }
    }
    float* op = out + ((long)((n << 8) + o)) * SS + (qt << 6) + sb;
    #pragma unroll
    for (int u = 0; u < 4; ++u) {
        #pragma unroll
        for (int k2 = 0; k2 < 4; ++k2) a[u][k2] *= invL[sb + (u << 2) + k2];
        *(f32x4*)(op + (u << 2)) = a[u];
    }
}

extern "C" void kernel_launch(void* const* d_in, const int* in_sizes, int n_in,
                              void* d_out, int out_size, void* d_ws, size_t ws_size,
                              hipStream_t stream) {
    const float* x   = (const float*)d_in[0];
    const float* Wq  = (const float*)d_in[1];
    const float* bq  = (const float*)d_in[2];
    const float* Wkv = (const float*)d_in[3];
    const float* bkv = (const float*)d_in[4];
    float* out = (float*)d_out;
    char* ws = (char*)d_ws;
    __bf16* qw = (__bf16*)(ws + QOFF);
    __bf16* kw = (__bf16*)(ws + KOFF);
    __bf16* vw = (__bf16*)(ws + VOFF);
    __bf16* wc = (__bf16*)(ws + WOFF);
    float*  bias = (float*)(ws + BOFF);

    int mcshift = -1;
    for (int ms = 3; ms >= 0; --ms) {
        size_t slots = (size_t)256 << ms;
        size_t need = (size_t)PAOFF + slots * 65536 + slots * 512;
        if (need <= ws_size) { mcshift = ms; break; }
    }
    int direct = (mcshift < 0) ? 1 : 0;
    if (direct) mcshift = 0;
    int chshift = 6 - mcshift;
    float* pacc = (float*)(ws + PAOFF);
    float2* pstats = (float2*)(ws + PAOFF + (((size_t)256 << mcshift) * 65536));

    prep_kernel<<<dim3(768), dim3(256), 0, stream>>>(Wq, bq, Wkv, bkv, wc, bias);
    proj_kernel<<<dim3(256), dim3(256), 0, stream>>>(x, wc, bias, qw, kw, vw);
    attn_kernel<<<dim3(256 << mcshift), dim3(256), 0, stream>>>(qw, kw, vw, out, pacc, pstats,
                                                                chshift, mcshift, direct);
    if (!direct)
        combine_kernel<<<dim3(1024), dim3(256), 0, stream>>>(pacc, pstats, out, chshift, mcshift);
}